// Round 1
// 291.533 us; speedup vs baseline: 1.2347x; 1.2347x over previous
//
#include <hip/hip_runtime.h>
#include <hip/hip_fp16.h>

#define N_NODES 50000
#define N_EDGES 800000
#define D 128
#define N_GRAPHS 64
#define NEG_SLOPE 0.01f
#define POOL_PARTS 8
#define ELLW 32      // 32 ushort slots = 64 B per node row
#define OVF_CAP 8192 // overflow pairs per branch; expected usage ~30

#define BUCKETS 196  // dst>>8 -> 196 buckets of 256 nodes
#define NPAD (BUCKETS * 256)
#define EPB 4096     // edges per phase-A block
#define BCAP 5120    // per-bucket capacity

typedef _Float16 half8 __attribute__((ext_vector_type(8)));
typedef _Float16 half4 __attribute__((ext_vector_type(4)));
typedef float f32x4 __attribute__((ext_vector_type(4)));
typedef float f32x2 __attribute__((ext_vector_type(2)));

// ---------------- W transpose+cast prep: WtH[w][n*128+k] = (half)W[k*128+n] ----------------
__global__ __launch_bounds__(256) void k_prep(const float* __restrict__ Wa, const float* __restrict__ Wb,
                                              const float* __restrict__ Wc, const float* __restrict__ Wd,
                                              __half* __restrict__ WtH) {
    const float* Ws[4] = {Wa, Wb, Wc, Wd};
    const float* W = Ws[blockIdx.x];
    __half* o = WtH + (size_t)blockIdx.x * 16384;
    int t = threadIdx.x;
    for (int r = 0; r < 64; r++) {
        int e = r * 256 + t;
        int k = e >> 7, n = e & 127;
        o[n * 128 + k] = __float2half(W[k * 128 + n]);
    }
}

// ---------------- Phase A: partition edges into dst-buckets (both branches, blockIdx.y) ----------------
__global__ __launch_bounds__(256) void k_part(const int* __restrict__ ei1, const int* __restrict__ ei2,
                                              int* __restrict__ gcnt, int2* __restrict__ bucketed) {
    const int br = blockIdx.y;
    const int* __restrict__ src = (br ? ei2 : ei1);
    const int* __restrict__ dst = src + N_EDGES;
    int* __restrict__ gc = gcnt + br * BUCKETS;
    int2* __restrict__ bk = bucketed + (size_t)br * BUCKETS * BCAP;

    __shared__ int bcnt[BUCKETS];
    __shared__ int bofs[BUCKETS];
    __shared__ int gbase[BUCKETS];
    __shared__ int2 stage[EPB];
    const int tid = threadIdx.x;
    const int base = blockIdx.x * EPB;
    for (int b = tid; b < BUCKETS; b += 256) bcnt[b] = 0;
    __syncthreads();
    int d_[16], s_[16], p_[16];
#pragma unroll
    for (int k = 0; k < 16; k++) {
        int i = base + k * 256 + tid;
        bool v = i < N_EDGES;
        d_[k] = v ? dst[i] : -1;
        s_[k] = v ? src[i] : 0;
        p_[k] = 0;
        if (v) p_[k] = atomicAdd(&bcnt[d_[k] >> 8], 1);
    }
    __syncthreads();
    if (tid == 0) {
        int run = 0;
        for (int b = 0; b < BUCKETS; b++) { bofs[b] = run; run += bcnt[b]; }
    }
    __syncthreads();
    if (tid < BUCKETS) gbase[tid] = atomicAdd(&gc[tid], bcnt[tid]);
    __syncthreads();
#pragma unroll
    for (int k = 0; k < 16; k++) {
        if (d_[k] >= 0) stage[bofs[d_[k] >> 8] + p_[k]] = make_int2(d_[k], s_[k]);
    }
    __syncthreads();
    int total = bofs[BUCKETS - 1] + bcnt[BUCKETS - 1];
    for (int i = tid; i < total; i += 256) {
        int2 e = stage[i];
        int b = e.x >> 8;
        int dest = gbase[b] + (i - bofs[b]);
        if (dest < BCAP) bk[(size_t)b * BCAP + dest] = e;
    }
}

// ---------------- Phase B: build ELL tile per bucket in LDS (both branches) ----------------
__global__ __launch_bounds__(256) void k_build(const int* __restrict__ gcnt, const int2* __restrict__ bucketed,
                                               int* __restrict__ cnti, unsigned short* __restrict__ ell,
                                               int2* __restrict__ ovf, int* __restrict__ ocnt) {
    const int br = blockIdx.y;
    const int* __restrict__ gc = gcnt + br * BUCKETS;
    const int2* __restrict__ bk = bucketed + (size_t)br * BUCKETS * BCAP;
    int* __restrict__ ci = cnti + br * NPAD;
    unsigned short* __restrict__ el = ell + (size_t)br * NPAD * ELLW;
    int2* __restrict__ ov = ovf + (size_t)br * OVF_CAP;
    int* __restrict__ oc = ocnt + br;

    __shared__ unsigned short lell[256 * ELLW];
    __shared__ int lcnt[256];
    const int b = blockIdx.x, tid = threadIdx.x;
    lcnt[tid] = 0;
    __syncthreads();
    int nb = min(gc[b], BCAP);
    const int2* __restrict__ bp = bk + (size_t)b * BCAP;
    for (int i = tid; i < nb; i += 256) {
        int2 e = bp[i];
        int dl = e.x & 255;
        int p = atomicAdd(&lcnt[dl], 1);
        if (p < ELLW) {
            lell[dl * ELLW + p] = (unsigned short)e.y;
        } else {
            int o = atomicAdd(oc, 1);
            if (o < OVF_CAP) ov[o] = e;
        }
    }
    __syncthreads();
    ci[b * 256 + tid] = lcnt[tid];
    uint4* eg = (uint4*)(el + (size_t)b * 256 * ELLW);
    const uint4* elc = (const uint4*)lell;
    for (int i = tid; i < 256 * ELLW * 2 / 16; i += 256) eg[i] = elc[i];
}

// ---------------- MFMA GEMM: H[N,128](fp8 e4m3) = (x @ W) * rsqrt(cnt+1), both branches ----------------
#define XS 136
template <bool FP16IN>
__global__ __launch_bounds__(256) void k_gemm(const void* __restrict__ xin1, const void* __restrict__ xin2,
                                              const __half* __restrict__ WtHall, int layer,
                                              const int* __restrict__ cnti, unsigned char* __restrict__ H8) {
    const int br = blockIdx.y;
    const void* __restrict__ xin = (br ? xin2 : xin1);
    const __half* __restrict__ WtH = WtHall + (size_t)(br * 2 + layer) * 16384;
    const int* __restrict__ cnt = cnti + br * NPAD;
    unsigned char* __restrict__ h = H8 + (size_t)br * N_NODES * 128;

    __shared__ _Float16 Xl[64 * XS];
    __shared__ _Float16 Wt[128 * XS];
    const int tid = threadIdx.x;
    const int w = tid >> 6, lane = tid & 63;
    const int quad = lane >> 4, l16 = lane & 15;
    const int row0 = blockIdx.x * 64;

#pragma unroll
    for (int i = 0; i < 8; i++) {
        int i2 = tid + 256 * i;
        int r = i2 >> 4, cg = i2 & 15;
        *(uint4*)&Wt[r * XS + cg * 8] = ((const uint4*)WtH)[i2];
    }
    if (FP16IN) {
        const __half* x = (const __half*)xin;
#pragma unroll
        for (int i = 0; i < 4; i++) {
            int i2 = tid + 256 * i;
            int r = i2 >> 4, cg = i2 & 15;
            uint4 v = make_uint4(0, 0, 0, 0);
            if (row0 + r < N_NODES) v = ((const uint4*)(x + (size_t)(row0 + r) * D))[cg];
            *(uint4*)&Xl[r * XS + cg * 8] = v;
        }
    } else {
        const float* x = (const float*)xin;
#pragma unroll
        for (int i = 0; i < 8; i++) {
            int i2 = tid + 256 * i;
            int r = i2 >> 5, f4 = i2 & 31;
            float4 v = make_float4(0.f, 0.f, 0.f, 0.f);
            if (row0 + r < N_NODES) v = *(const float4*)((const float*)x + (size_t)(row0 + r) * D + f4 * 4);
            half4 hv;
            hv[0] = (_Float16)v.x; hv[1] = (_Float16)v.y; hv[2] = (_Float16)v.z; hv[3] = (_Float16)v.w;
            *(half4*)&Xl[r * XS + f4 * 4] = hv;
        }
    }
    __syncthreads();

    half8 a[4];
#pragma unroll
    for (int kb = 0; kb < 4; kb++)
        a[kb] = *(const half8*)&Xl[(w * 16 + l16) * XS + kb * 32 + quad * 8];

    const int rbase = row0 + w * 16 + quad * 4;
    float di[4];
#pragma unroll
    for (int reg = 0; reg < 4; reg++) {
        int r = rbase + reg;
        di[reg] = (r < N_NODES) ? rsqrtf((float)cnt[r] + 1.0f) : 0.0f;
    }

    float accs[8][4];
#pragma unroll
    for (int ct = 0; ct < 8; ct++) {
        f32x4 acc = {0.f, 0.f, 0.f, 0.f};
#pragma unroll
        for (int kb = 0; kb < 4; kb++) {
            half8 b = *(const half8*)&Wt[(ct * 16 + l16) * XS + kb * 32 + quad * 8];
            acc = __builtin_amdgcn_mfma_f32_16x16x32_f16(a[kb], b, acc, 0, 0, 0);
        }
#pragma unroll
        for (int reg = 0; reg < 4; reg++) accs[ct][reg] = acc[reg] * di[reg];
    }

    // fp8 epilogue: stage 64x128 bytes in LDS (reuse Xl), then coalesced 16B stores
    __syncthreads();
    unsigned char* S = (unsigned char*)Xl;
#pragma unroll
    for (int ct = 0; ct < 8; ct++)
#pragma unroll
        for (int reg = 0; reg < 4; reg++) {
            int p = __builtin_amdgcn_cvt_pk_fp8_f32(accs[ct][reg], accs[ct][reg], 0, false);
            S[(w * 16 + quad * 4 + reg) * 128 + ct * 16 + l16] = (unsigned char)p;
        }
    __syncthreads();
#pragma unroll
    for (int i = 0; i < 2; i++) {
        int idx = tid + 256 * i;
        int r = idx >> 3, cg = idx & 7;
        if (row0 + r < N_NODES)
            ((uint4*)(h + (size_t)(row0 + r) * 128))[cg] = ((const uint4*)S)[idx];
    }
}

// ---------------- ELL aggregation: 2 nodes/wave, 32 lanes/node, both branches ----------------
// out(fp16)[d] = leaky( dinv[d] * (H[d] + sum H[src]) + bias )
__global__ __launch_bounds__(256) void k_agg(const int* __restrict__ cnti, const unsigned short* __restrict__ ell,
                                             const int2* __restrict__ ovf, const int* __restrict__ ocnt,
                                             const unsigned char* __restrict__ H8all, const float* __restrict__ bias1,
                                             const float* __restrict__ bias2, __half* __restrict__ ACT) {
    const int br = blockIdx.y;
    const int* __restrict__ cnt = cnti + br * NPAD;
    const unsigned short* __restrict__ el = ell + (size_t)br * NPAD * ELLW;
    const int2* __restrict__ ov = ovf + (size_t)br * OVF_CAP;
    const unsigned char* __restrict__ H8 = H8all + (size_t)br * N_NODES * 128;
    const float* __restrict__ bias = (br ? bias2 : bias1);
    __half* __restrict__ out = ACT + (size_t)br * N_NODES * D;

    const int tid = threadIdx.x;
    const int l32 = tid & 31;                 // lane within half-wave
    const int node = blockIdx.x * 8 + (tid >> 5);  // 8 halves per block
    int n = cnt[node];
    int nc = min(n, ELLW);
    // preload this half's edge list: lane l32 holds slot l32 (0 if beyond count)
    int sv = 0;
    if (l32 < nc) sv = (int)el[(size_t)node * ELLW + l32];
    // wave-uniform loop bound = max(ncA, ncB)
    int ncOther = __shfl(nc, (tid & 63) ^ 32, 64);
    int jmax = max(nc, ncOther);

    float4 acc[8];
    {
        unsigned int dw = *(const unsigned int*)(H8 + (size_t)node * 128 + l32 * 4);
        f32x2 lo = __builtin_amdgcn_cvt_pk_f32_fp8((int)dw, false);
        f32x2 hi = __builtin_amdgcn_cvt_pk_f32_fp8((int)dw, true);
        acc[0] = make_float4(lo[0], lo[1], hi[0], hi[1]);  // self term (already dinv-scaled)
    }
#pragma unroll
    for (int i = 1; i < 8; i++) acc[i] = make_float4(0.f, 0.f, 0.f, 0.f);

    for (int j = 0; j < jmax; j += 8) {
        int s[8]; float w[8];
#pragma unroll
        for (int i = 0; i < 8; i++) {
            s[i] = __shfl(sv, j + i, 32);      // broadcast within this half; 0 if slot empty
            w[i] = ((j + i) < nc) ? 1.0f : 0.0f;
        }
#pragma unroll
        for (int i = 0; i < 8; i++) {
            unsigned int dw = *(const unsigned int*)(H8 + (size_t)s[i] * 128 + l32 * 4);
            f32x2 lo = __builtin_amdgcn_cvt_pk_f32_fp8((int)dw, false);
            f32x2 hi = __builtin_amdgcn_cvt_pk_f32_fp8((int)dw, true);
            acc[i].x = fmaf(w[i], lo[0], acc[i].x);
            acc[i].y = fmaf(w[i], lo[1], acc[i].y);
            acc[i].z = fmaf(w[i], hi[0], acc[i].z);
            acc[i].w = fmaf(w[i], hi[1], acc[i].w);
        }
    }
    if (n > ELLW) {  // rare overflow path
        int oc = min(ocnt[br], OVF_CAP);
        for (int o = 0; o < oc; o++) {
            int2 p = ov[o];
            if (p.x == node) {
                unsigned int dw = *(const unsigned int*)(H8 + (size_t)p.y * 128 + l32 * 4);
                f32x2 lo = __builtin_amdgcn_cvt_pk_f32_fp8((int)dw, false);
                f32x2 hi = __builtin_amdgcn_cvt_pk_f32_fp8((int)dw, true);
                acc[0].x += lo[0]; acc[0].y += lo[1]; acc[0].z += hi[0]; acc[0].w += hi[1];
            }
        }
    }
    float sx = ((acc[0].x + acc[1].x) + (acc[2].x + acc[3].x)) + ((acc[4].x + acc[5].x) + (acc[6].x + acc[7].x));
    float sy = ((acc[0].y + acc[1].y) + (acc[2].y + acc[3].y)) + ((acc[4].y + acc[5].y) + (acc[6].y + acc[7].y));
    float sz = ((acc[0].z + acc[1].z) + (acc[2].z + acc[3].z)) + ((acc[4].z + acc[5].z) + (acc[6].z + acc[7].z));
    float sw = ((acc[0].w + acc[1].w) + (acc[2].w + acc[3].w)) + ((acc[4].w + acc[5].w) + (acc[6].w + acc[7].w));
    float dv = rsqrtf((float)n + 1.0f);
    float4 b = ((const float4*)bias)[l32];
    float vx = sx * dv + b.x;
    float vy = sy * dv + b.y;
    float vz = sz * dv + b.z;
    float vw = sw * dv + b.w;
    vx = vx > 0.0f ? vx : NEG_SLOPE * vx;
    vy = vy > 0.0f ? vy : NEG_SLOPE * vy;
    vz = vz > 0.0f ? vz : NEG_SLOPE * vz;
    vw = vw > 0.0f ? vw : NEG_SLOPE * vw;
    union { __half2 h2[2]; uint2 u; } up;
    up.h2[0] = __floats2half2_rn(vx, vy);
    up.h2[1] = __floats2half2_rn(vz, vw);
    *(uint2*)(out + (size_t)node * 128 + l32 * 4) = up.u;
}

// ---------------- mean pool (fp16 in): per-(graph,part) float partials, both branches ----------------
__device__ __forceinline__ int lower_bound_i(const int* __restrict__ arr, int n, int key) {
    int lo = 0, hi = n;
    while (lo < hi) {
        int mid = (lo + hi) >> 1;
        if (arr[mid] < key) lo = mid + 1; else hi = mid;
    }
    return lo;
}

__global__ __launch_bounds__(256) void k_pool(const __half* __restrict__ ACT, const int* __restrict__ batch1,
                                              const int* __restrict__ batch2, float* __restrict__ ppall,
                                              float* __restrict__ cntall) {
    const int br = blockIdx.z;
    const __half* __restrict__ h = ACT + (size_t)br * N_NODES * D;
    const int* __restrict__ batch = (br ? batch2 : batch1);
    float* __restrict__ pp = ppall + (size_t)br * N_GRAPHS * POOL_PARTS * D;
    float* __restrict__ cnt = cntall + br * N_GRAPHS;

    int g = blockIdx.x;
    int part = blockIdx.y;
    int lo = lower_bound_i(batch, N_NODES, g);
    int hi = lower_bound_i(batch, N_NODES, g + 1);
    int num = hi - lo;
    if (part == 0 && threadIdx.x == 0) cnt[g] = (float)num;
    int chunk = (num + POOL_PARTS - 1) / POOL_PARTS;
    int a = lo + part * chunk;
    int b = min(a + chunk, hi);
    int c2 = threadIdx.x & 63;
    int sub = threadIdx.x >> 6;
    const __half2* __restrict__ h2 = (const __half2*)h;
    float2 acc = make_float2(0.f, 0.f);
    for (int node = a + sub; node < b; node += 4) {
        float2 v = __half22float2(h2[(size_t)node * 64 + c2]);
        acc.x += v.x; acc.y += v.y;
    }
    __shared__ float2 tmp[256];
    tmp[threadIdx.x] = acc;
    __syncthreads();
    if (sub == 0) {
        float2 s;
        s.x = tmp[c2].x + tmp[c2 + 64].x + tmp[c2 + 128].x + tmp[c2 + 192].x;
        s.y = tmp[c2].y + tmp[c2 + 64].y + tmp[c2 + 128].y + tmp[c2 + 192].y;
        ((float2*)pp)[((size_t)g * POOL_PARTS + part) * 64 + c2] = s;
    }
}

// ---------------- final MLP (reduces pool parts) ----------------
__global__ __launch_bounds__(128) void k_mlp(const float* __restrict__ pp1, const float* __restrict__ pp2,
                                             const float* __restrict__ cnt1, const float* __restrict__ cnt2,
                                             const float* __restrict__ lin1W, const float* __restrict__ lin1b,
                                             const float* __restrict__ lin2W, const float* __restrict__ lin2b,
                                             float* __restrict__ out) {
    int g = blockIdx.x;
    int c = threadIdx.x;
    __shared__ float cat[2 * D];
    float s1 = 0.f, s2 = 0.f;
#pragma unroll
    for (int p = 0; p < POOL_PARTS; p++) {
        s1 += pp1[((size_t)g * POOL_PARTS + p) * D + c];
        s2 += pp2[((size_t)g * POOL_PARTS + p) * D + c];
    }
    cat[c] = s1 / fmaxf(cnt1[g], 1.0f);
    cat[c + D] = s2 / fmaxf(cnt2[g], 1.0f);
    __syncthreads();
    float acc = lin1b[c];
#pragma unroll 8
    for (int k = 0; k < 2 * D; k++) acc += cat[k] * lin1W[k * D + c];
    acc = fmaxf(acc, 0.0f);
    float v = acc * lin2W[c];
#pragma unroll
    for (int off = 32; off > 0; off >>= 1) v += __shfl_down(v, off, 64);
    __shared__ float wsum[2];
    if ((c & 63) == 0) wsum[c >> 6] = v;
    __syncthreads();
    if (c == 0) out[g] = wsum[0] + wsum[1] + lin2b[0];
}

extern "C" void kernel_launch(void* const* d_in, const int* in_sizes, int n_in,
                              void* d_out, int out_size, void* d_ws, size_t ws_size,
                              hipStream_t stream) {
    const float* x1 = (const float*)d_in[0];
    const int*   ei1 = (const int*)d_in[1];
    const int*   batch1 = (const int*)d_in[2];
    const float* x2 = (const float*)d_in[3];
    const int*   ei2 = (const int*)d_in[4];
    const int*   batch2 = (const int*)d_in[5];
    const float* W1_0 = (const float*)d_in[6];
    const float* b1_0 = (const float*)d_in[7];
    const float* W1_1 = (const float*)d_in[8];
    const float* b1_1 = (const float*)d_in[9];
    const float* W2_0 = (const float*)d_in[10];
    const float* b2_0 = (const float*)d_in[11];
    const float* W2_1 = (const float*)d_in[12];
    const float* b2_1 = (const float*)d_in[13];
    const float* lin1W = (const float*)d_in[14];
    const float* lin1b = (const float*)d_in[15];
    const float* lin2W = (const float*)d_in[16];
    const float* lin2b = (const float*)d_in[17];
    float* out = (float*)d_out;

    // ---- workspace layout: per-branch duplicated so both branches run in one dispatch ----
    __half* WtH = (__half*)d_ws;                                   // 4*16384 halves (128 KB)
    __half* ACT = WtH + 65536;                                     // 2 * N*D halves
    unsigned char* H8 = (unsigned char*)(ACT + 2 * (size_t)N_NODES * D);  // 2 * N*128 bytes
    int*    cnti = (int*)(H8 + 2 * (size_t)N_NODES * 128);         // 2 * NPAD ints
    int*    gcnt = cnti + 2 * NPAD;                                // 2 * BUCKETS
    int*    ocnt = gcnt + 2 * BUCKETS;                             // 2 (+ pad to 8)
    int2*   ovf  = (int2*)(ocnt + 8);                              // 2 * OVF_CAP pairs
    unsigned short* ell = (unsigned short*)(ovf + 2 * (size_t)OVF_CAP);   // 2 * NPAD*ELLW ushorts
    int2*   bucketed = (int2*)(ell + 2 * (size_t)NPAD * ELLW);     // 2 * BUCKETS*BCAP pairs
    float*  pp  = (float*)(bucketed + 2 * (size_t)BUCKETS * BCAP); // 2 * G*PARTS*D
    float*  cnt = pp + 2 * (size_t)N_GRAPHS * POOL_PARTS * D;      // 2 * G

    dim3 b256(256);
    int partBlocks = (N_EDGES + EPB - 1) / EPB;  // 196
    int gemmBlocks = (N_NODES + 63) / 64;        // 782
    int aggBlocks  = N_NODES / 8;                // 6250

    k_prep<<<4, b256, 0, stream>>>(W1_0, W1_1, W2_0, W2_1, WtH);
    hipMemsetAsync(gcnt, 0, (2 * BUCKETS + 8) * sizeof(int), stream);

    // both branches per dispatch (blockIdx.y / blockIdx.z = branch)
    k_part <<<dim3(partBlocks, 2), b256, 0, stream>>>(ei1, ei2, gcnt, bucketed);
    k_build<<<dim3(BUCKETS, 2),    b256, 0, stream>>>(gcnt, bucketed, cnti, ell, ovf, ocnt);

    k_gemm<false><<<dim3(gemmBlocks, 2), b256, 0, stream>>>(x1, x2, WtH, 0, cnti, H8);
    k_agg        <<<dim3(aggBlocks, 2),  b256, 0, stream>>>(cnti, ell, ovf, ocnt, H8, b1_0, b2_0, ACT);
    k_gemm<true> <<<dim3(gemmBlocks, 2), b256, 0, stream>>>(ACT, ACT + (size_t)N_NODES * D, WtH, 1, cnti, H8);
    k_agg        <<<dim3(aggBlocks, 2),  b256, 0, stream>>>(cnti, ell, ovf, ocnt, H8, b1_1, b2_1, ACT);

    k_pool<<<dim3(N_GRAPHS, POOL_PARTS, 2), b256, 0, stream>>>(ACT, batch1, batch2, pp, cnt);

    k_mlp<<<N_GRAPHS, dim3(128), 0, stream>>>(pp, pp + (size_t)N_GRAPHS * POOL_PARTS * D,
                                              cnt, cnt + N_GRAPHS,
                                              lin1W, lin1b, lin2W, lin2b, out);
}